// Round 1
// baseline (356.504 us; speedup 1.0000x reference)
//
#include <hip/hip_runtime.h>
#include <math.h>

#define TRANS_SCALE 0.1f

// ---------------------------------------------------------------------------
// Kernel 1: per-batch affine matrix.
//   w       = softplus(width)                    (6,)
//   weights = rand_u * w - w/2                   (B,6)
//   G       = sum of scaled Lie generators       (B,3,3)
//   A       = expm(G)  (Taylor order 10, 6 scaling-and-squaring steps,
//                       same op order as reference for fp32 fidelity)
//   theta   = A[:2,:]  -> 6 floats per batch into d_ws
// ---------------------------------------------------------------------------
__global__ void uaug_theta_kernel(const float* __restrict__ width,
                                  const float* __restrict__ rand_u,
                                  float* __restrict__ theta, int B) {
    int b = blockIdx.x * blockDim.x + threadIdx.x;
    if (b >= B) return;

    float wt[6];
#pragma unroll
    for (int i = 0; i < 6; ++i) {
        float wd = width[i];
        // numerically-stable softplus, matches jax.nn.softplus
        float sp = log1pf(expf(-fabsf(wd))) + fmaxf(wd, 0.0f);
        wt[i] = rand_u[b * 6 + i] * sp - sp * 0.5f;
    }

    float G[3][3];
#pragma unroll
    for (int i = 0; i < 3; ++i)
#pragma unroll
        for (int j = 0; j < 3; ++j) G[i][j] = 0.0f;
    G[0][2] = wt[0] * TRANS_SCALE;
    G[1][2] = wt[1] * TRANS_SCALE;
    G[0][1] = -wt[2] + wt[5];
    G[1][0] = wt[2] + wt[5];
    G[0][0] = wt[3] + wt[4];
    G[1][1] = wt[3] - wt[4];

    // A = G / 2^6
    const float scale = 1.0f / 64.0f;
    float A[3][3];
#pragma unroll
    for (int i = 0; i < 3; ++i)
#pragma unroll
        for (int j = 0; j < 3; ++j) A[i][j] = G[i][j] * scale;

    // Taylor: out = I + sum_{k=1..10} A^k / k!
    float term[3][3], out[3][3];
#pragma unroll
    for (int i = 0; i < 3; ++i)
#pragma unroll
        for (int j = 0; j < 3; ++j) {
            float v = (i == j) ? 1.0f : 0.0f;
            term[i][j] = v;
            out[i][j] = v;
        }
#pragma unroll
    for (int k = 1; k <= 10; ++k) {
        float t2[3][3];
        float inv = 1.0f / (float)k;
#pragma unroll
        for (int i = 0; i < 3; ++i)
#pragma unroll
            for (int j = 0; j < 3; ++j) {
                float s = 0.0f;
#pragma unroll
                for (int l = 0; l < 3; ++l) s += term[i][l] * A[l][j];
                t2[i][j] = s * inv;
            }
#pragma unroll
        for (int i = 0; i < 3; ++i)
#pragma unroll
            for (int j = 0; j < 3; ++j) {
                term[i][j] = t2[i][j];
                out[i][j] += t2[i][j];
            }
    }
    // 6 squarings
#pragma unroll
    for (int s = 0; s < 6; ++s) {
        float t2[3][3];
#pragma unroll
        for (int i = 0; i < 3; ++i)
#pragma unroll
            for (int j = 0; j < 3; ++j) {
                float acc = 0.0f;
#pragma unroll
                for (int l = 0; l < 3; ++l) acc += out[i][l] * out[l][j];
                t2[i][j] = acc;
            }
#pragma unroll
        for (int i = 0; i < 3; ++i)
#pragma unroll
            for (int j = 0; j < 3; ++j) out[i][j] = t2[i][j];
    }

    theta[b * 6 + 0] = out[0][0];
    theta[b * 6 + 1] = out[0][1];
    theta[b * 6 + 2] = out[0][2];
    theta[b * 6 + 3] = out[1][0];
    theta[b * 6 + 4] = out[1][1];
    theta[b * 6 + 5] = out[1][2];
}

// ---------------------------------------------------------------------------
// Kernel 2: affine grid + bilinear grid_sample (zeros padding, align_corners).
// One thread per (b,h,w) pixel; handles all C channels.
// ---------------------------------------------------------------------------
__global__ __launch_bounds__(256) void uaug_sample_kernel(
    const float* __restrict__ img, const float* __restrict__ theta,
    float* __restrict__ out, int B, int C, int H, int W) {
    int idx = blockIdx.x * blockDim.x + threadIdx.x;
    int total = B * H * W;
    if (idx >= total) return;

    int wc = idx % W;
    int t = idx / W;
    int hc = t % H;
    int b = t / H;

    float xs = -1.0f + 2.0f * (float)wc / (float)(W - 1);
    float ys = -1.0f + 2.0f * (float)hc / (float)(H - 1);

    const float* th = theta + b * 6;
    float gx = th[0] * xs + th[1] * ys + th[2];
    float gy = th[3] * xs + th[4] * ys + th[5];

    float ix = (gx + 1.0f) * 0.5f * (float)(W - 1);
    float iy = (gy + 1.0f) * 0.5f * (float)(H - 1);

    float ix0f = floorf(ix);
    float iy0f = floorf(iy);
    float wx1 = ix - ix0f;
    float wy1 = iy - iy0f;
    float wx0 = 1.0f - wx1;
    float wy0 = 1.0f - wy1;

    int ix0 = (int)ix0f;
    int iy0 = (int)iy0f;
    int ix1 = ix0 + 1;
    int iy1 = iy0 + 1;

    bool vx0 = (ix0 >= 0) && (ix0 < W);
    bool vx1 = (ix1 >= 0) && (ix1 < W);
    bool vy0 = (iy0 >= 0) && (iy0 < H);
    bool vy1 = (iy1 >= 0) && (iy1 < H);

    int cx0 = min(max(ix0, 0), W - 1);
    int cx1 = min(max(ix1, 0), W - 1);
    int cy0 = min(max(iy0, 0), H - 1);
    int cy1 = min(max(iy1, 0), H - 1);

    float w00 = wy0 * wx0 * ((vy0 && vx0) ? 1.0f : 0.0f);
    float w01 = wy0 * wx1 * ((vy0 && vx1) ? 1.0f : 0.0f);
    float w10 = wy1 * wx0 * ((vy1 && vx0) ? 1.0f : 0.0f);
    float w11 = wy1 * wx1 * ((vy1 && vx1) ? 1.0f : 0.0f);

    size_t HW = (size_t)H * W;
    const float* base = img + (size_t)b * C * HW;
    size_t o00 = (size_t)cy0 * W + cx0;
    size_t o01 = (size_t)cy0 * W + cx1;
    size_t o10 = (size_t)cy1 * W + cx0;
    size_t o11 = (size_t)cy1 * W + cx1;

    float* ob = out + (size_t)b * C * HW + (size_t)hc * W + wc;
#pragma unroll
    for (int c = 0; c < 3; ++c) {
        const float* p = base + (size_t)c * HW;
        float v = p[o00] * w00 + p[o01] * w01 + p[o10] * w10 + p[o11] * w11;
        ob[(size_t)c * HW] = v;
    }
}

extern "C" void kernel_launch(void* const* d_in, const int* in_sizes, int n_in,
                              void* d_out, int out_size, void* d_ws, size_t ws_size,
                              hipStream_t stream) {
    const float* x      = (const float*)d_in[0];
    const float* width  = (const float*)d_in[1];
    const float* rand_u = (const float*)d_in[2];
    float* out = (float*)d_out;

    int B = in_sizes[2] / 6;           // 256
    int C = 3, H = 224, W = 224;

    float* theta = (float*)d_ws;        // B*6 floats = 6 KiB

    uaug_theta_kernel<<<(B + 255) / 256, 256, 0, stream>>>(width, rand_u, theta, B);

    int total = B * H * W;              // 12,845,056
    uaug_sample_kernel<<<(total + 255) / 256, 256, 0, stream>>>(x, theta, out, B, C, H, W);
}

// Round 4
// 352.408 us; speedup vs baseline: 1.0116x; 1.0116x over previous
//
#include <hip/hip_runtime.h>
#include <math.h>

#define TRANS_SCALE 0.1f

// ---------------------------------------------------------------------------
// Kernel 1: per-batch affine matrix (B=256 threads total; trivial cost).
// ---------------------------------------------------------------------------
__global__ void uaug_theta_kernel(const float* __restrict__ width,
                                  const float* __restrict__ rand_u,
                                  float* __restrict__ theta, int B) {
    int b = blockIdx.x * blockDim.x + threadIdx.x;
    if (b >= B) return;

    float wt[6];
#pragma unroll
    for (int i = 0; i < 6; ++i) {
        float wd = width[i];
        float sp = log1pf(expf(-fabsf(wd))) + fmaxf(wd, 0.0f);  // softplus
        wt[i] = rand_u[b * 6 + i] * sp - sp * 0.5f;
    }

    float G[3][3];
#pragma unroll
    for (int i = 0; i < 3; ++i)
#pragma unroll
        for (int j = 0; j < 3; ++j) G[i][j] = 0.0f;
    G[0][2] = wt[0] * TRANS_SCALE;
    G[1][2] = wt[1] * TRANS_SCALE;
    G[0][1] = -wt[2] + wt[5];
    G[1][0] = wt[2] + wt[5];
    G[0][0] = wt[3] + wt[4];
    G[1][1] = wt[3] - wt[4];

    const float scale = 1.0f / 64.0f;
    float A[3][3];
#pragma unroll
    for (int i = 0; i < 3; ++i)
#pragma unroll
        for (int j = 0; j < 3; ++j) A[i][j] = G[i][j] * scale;

    float term[3][3], out[3][3];
#pragma unroll
    for (int i = 0; i < 3; ++i)
#pragma unroll
        for (int j = 0; j < 3; ++j) {
            float v = (i == j) ? 1.0f : 0.0f;
            term[i][j] = v;
            out[i][j] = v;
        }
#pragma unroll
    for (int k = 1; k <= 10; ++k) {
        float t2[3][3];
        float inv = 1.0f / (float)k;
#pragma unroll
        for (int i = 0; i < 3; ++i)
#pragma unroll
            for (int j = 0; j < 3; ++j) {
                float s = 0.0f;
#pragma unroll
                for (int l = 0; l < 3; ++l) s += term[i][l] * A[l][j];
                t2[i][j] = s * inv;
            }
#pragma unroll
        for (int i = 0; i < 3; ++i)
#pragma unroll
            for (int j = 0; j < 3; ++j) {
                term[i][j] = t2[i][j];
                out[i][j] += t2[i][j];
            }
    }
#pragma unroll
    for (int s = 0; s < 6; ++s) {
        float t2[3][3];
#pragma unroll
        for (int i = 0; i < 3; ++i)
#pragma unroll
            for (int j = 0; j < 3; ++j) {
                float acc = 0.0f;
#pragma unroll
                for (int l = 0; l < 3; ++l) acc += out[i][l] * out[l][j];
                t2[i][j] = acc;
            }
#pragma unroll
        for (int i = 0; i < 3; ++i)
#pragma unroll
            for (int j = 0; j < 3; ++j) out[i][j] = t2[i][j];
    }

    theta[b * 6 + 0] = out[0][0];
    theta[b * 6 + 1] = out[0][1];
    theta[b * 6 + 2] = out[0][2];
    theta[b * 6 + 3] = out[1][0];
    theta[b * 6 + 4] = out[1][1];
    theta[b * 6 + 5] = out[1][2];
}

// ---------------------------------------------------------------------------
// Kernel 2: affine grid + bilinear grid_sample, fp32, zeros padding,
// align_corners=True.
//
// Geometry: H=W=224 -> 50176 px/image = 196 blocks of 256 exactly, so every
// block lies inside ONE image and `b` is block-uniform (scalar theta loads).
// XCD swizzle: 50176 blocks = 8 XCDs x 6272; contiguous chunk per XCD keeps
// the y0/y1 row reuse inside one L2 (fix for the 2.6x FETCH over-read).
// ---------------------------------------------------------------------------
#define IMG_W 224
#define IMG_H 224
#define BLOCKS_PER_IMG 196   /* 224*224/256 */

__global__ __launch_bounds__(256) void uaug_sample_kernel(
    const float* __restrict__ img, const float* __restrict__ theta,
    float* __restrict__ out) {
    // --- XCD-contiguous block swizzle (grid = 50176, divisible by 8) ---
    int bid = blockIdx.x;
    int chunk = gridDim.x >> 3;                 // 6272
    int swz = (bid & 7) * chunk + (bid >> 3);

    int b = swz / BLOCKS_PER_IMG;               // block-uniform image index
    int rem = swz - b * BLOCKS_PER_IMG;
    int pix = rem * 256 + threadIdx.x;          // pixel index within image
    int hc = pix / IMG_W;
    int wc = pix - hc * IMG_W;

    // scalar (uniform) theta
    const float* th = theta + b * 6;
    float t0 = th[0], t1 = th[1], t2 = th[2];
    float t3 = th[3], t4 = th[4], t5 = th[5];

    const float inv = 2.0f / (float)(IMG_W - 1);     // == 2/(H-1) too
    float xs = (float)wc * inv - 1.0f;
    float ys = (float)hc * inv - 1.0f;

    float gx = t0 * xs + t1 * ys + t2;
    float gy = t3 * xs + t4 * ys + t5;

    float ix = (gx + 1.0f) * 0.5f * (float)(IMG_W - 1);
    float iy = (gy + 1.0f) * 0.5f * (float)(IMG_H - 1);

    float ix0f = floorf(ix);
    float iy0f = floorf(iy);
    float wx1 = ix - ix0f;
    float wy1 = iy - iy0f;
    float wx0 = 1.0f - wx1;
    float wy0 = 1.0f - wy1;

    int ix0 = (int)ix0f;
    int iy0 = (int)iy0f;
    int ix1 = ix0 + 1;
    int iy1 = iy0 + 1;

    bool vx0 = (ix0 >= 0) && (ix0 < IMG_W);
    bool vx1 = (ix1 >= 0) && (ix1 < IMG_W);
    bool vy0 = (iy0 >= 0) && (iy0 < IMG_H);
    bool vy1 = (iy1 >= 0) && (iy1 < IMG_H);

    int cx0 = min(max(ix0, 0), IMG_W - 1);
    int cx1 = min(max(ix1, 0), IMG_W - 1);
    int cy0 = min(max(iy0, 0), IMG_H - 1);
    int cy1 = min(max(iy1, 0), IMG_H - 1);

    float w00 = wy0 * wx0 * ((vy0 && vx0) ? 1.0f : 0.0f);
    float w01 = wy0 * wx1 * ((vy0 && vx1) ? 1.0f : 0.0f);
    float w10 = wy1 * wx0 * ((vy1 && vx0) ? 1.0f : 0.0f);
    float w11 = wy1 * wx1 * ((vy1 && vx1) ? 1.0f : 0.0f);

    const int HW = IMG_H * IMG_W;               // 50176
    // scalar base addresses (b uniform)
    const float* basec = img + (size_t)b * (3 * HW);
    float* ob = out + (size_t)b * (3 * HW) + pix;

    // 32-bit per-lane offsets
    int o00 = cy0 * IMG_W + cx0;
    int o01 = cy0 * IMG_W + cx1;
    int o10 = cy1 * IMG_W + cx0;
    int o11 = cy1 * IMG_W + cx1;

#pragma unroll
    for (int c = 0; c < 3; ++c) {
        const float* p = basec + c * HW;
        float v = p[o00] * w00 + p[o01] * w01 + p[o10] * w10 + p[o11] * w11;
        __builtin_nontemporal_store(v, ob + c * HW);
    }
}

extern "C" void kernel_launch(void* const* d_in, const int* in_sizes, int n_in,
                              void* d_out, int out_size, void* d_ws, size_t ws_size,
                              hipStream_t stream) {
    const float* x      = (const float*)d_in[0];
    const float* width  = (const float*)d_in[1];
    const float* rand_u = (const float*)d_in[2];
    float* out = (float*)d_out;

    int B = in_sizes[2] / 6;            // 256

    float* theta = (float*)d_ws;        // B*6 floats

    uaug_theta_kernel<<<(B + 255) / 256, 256, 0, stream>>>(width, rand_u, theta, B);

    int total = B * IMG_H * IMG_W;      // 12,845,056
    uaug_sample_kernel<<<total / 256, 256, 0, stream>>>(x, theta, out);
}